// Round 3
// baseline (713.322 us; speedup 1.0000x reference)
//
#include <hip/hip_runtime.h>
#include <hip/hip_cooperative_groups.h>
#include <cfloat>
#include <cmath>

namespace cg = cooperative_groups;

#define H 1024
#define V 50257
#define L 128
#define NBLK 512
#define NTHR 256
#define NWAVE (NBLK * 4)        // 2048 waves grid-wide

// ws layout (float offsets)
#define WS_COMB_IN 0            // [2048] = embedded[1024] ++ attn_applied[1024]
#define WS_SC      2048         // [128]  attention scores
#define WS_X       2176        // [1024] relu(comb)
#define WS_HN      3200         // [1024] h_new
#define WS_PM      4224         // [NBLK] per-block max partial
#define WS_PS      5248         // [NBLK] per-block sumexp partial
#define WS_LOGITS  6400         // [V]

__device__ __forceinline__ float dot4(float4 a, float4 b) {
    return a.x * b.x + a.y * b.y + a.z * b.z + a.w * b.w;
}

__device__ __forceinline__ float wave_sum(float acc) {
    #pragma unroll
    for (int off = 32; off > 0; off >>= 1) acc += __shfl_down(acc, off);
    return acc;
}

__device__ __forceinline__ float sigmoidf(float x) {
    return 1.f / (1.f + expf(-x));
}

__global__ __launch_bounds__(NTHR, 2) void fused_decoder(
        const int* __restrict__ tokens,
        const float* __restrict__ h0,
        const float* __restrict__ c0,
        const float* __restrict__ enc,
        const float* __restrict__ emb,
        const float* __restrict__ attn_W,
        const float* __restrict__ attn_b,
        const float* __restrict__ comb_W,
        const float* __restrict__ comb_b,
        const float* __restrict__ W_ih,
        const float* __restrict__ W_hh,
        const float* __restrict__ b_ih,
        const float* __restrict__ b_hh,
        const float* __restrict__ out_W,
        const float* __restrict__ out_b,
        float* __restrict__ dout,
        float* __restrict__ ws) {
    cg::grid_group grid = cg::this_grid();
    const int b = blockIdx.x, t = threadIdx.x;
    const int w = t >> 6, lane = t & 63;
    const int gw = b * 4 + w;

    __shared__ float s_aw[L];
    __shared__ float s_redA[NTHR];
    __shared__ float s_redB[NTHR];
    __shared__ float s_g4[4];

    // ---- Phase 0: attention scores (waves 0..127 = blocks 0..31);
    //      embedded copy to ws (blocks 32..35) ----
    if (gw < L) {
        const int token = tokens[0];
        const float4* wrow = (const float4*)(attn_W + (size_t)gw * (2 * H));
        const float4* ev   = (const float4*)(emb + (size_t)token * H);
        const float4* hv   = (const float4*)h0;
        float acc = 0.f;
        #pragma unroll
        for (int it = 0; it < 4; ++it) acc += dot4(wrow[lane + it * 64], ev[lane + it * 64]);
        #pragma unroll
        for (int it = 0; it < 4; ++it) acc += dot4(wrow[256 + lane + it * 64], hv[lane + it * 64]);
        acc = wave_sum(acc);
        if (lane == 0) ws[WS_SC + gw] = acc + attn_b[gw];
    } else if (b >= 32 && b < 36) {
        const int token = tokens[0];
        const int idx = (b - 32) * NTHR + t;
        ws[WS_COMB_IN + idx] = emb[(size_t)token * H + idx];
    }
    grid.sync();

    // ---- Phase 1: softmax (recomputed in blocks 0..3) + attn_applied ----
    if (b < 4) {
        float sv = (t < L) ? ws[WS_SC + t] : -FLT_MAX;
        s_redA[t] = sv;
        __syncthreads();
        #pragma unroll
        for (int s = 128; s > 0; s >>= 1) {
            if (t < s) s_redA[t] = fmaxf(s_redA[t], s_redA[t + s]);
            __syncthreads();
        }
        const float m = s_redA[0];
        __syncthreads();
        const float e = (t < L) ? expf(sv - m) : 0.f;
        s_redA[t] = e;
        __syncthreads();
        #pragma unroll
        for (int s = 128; s > 0; s >>= 1) {
            if (t < s) s_redA[t] += s_redA[t + s];
            __syncthreads();
        }
        const float inv = 1.f / s_redA[0];
        if (t < L) s_aw[t] = e * inv;
        __syncthreads();
        // attn_applied column j
        const int j = b * NTHR + t;
        float a = 0.f;
        #pragma unroll 4
        for (int l = 0; l < L; ++l) a += s_aw[l] * enc[l * H + j];
        ws[WS_COMB_IN + H + j] = a;
        if (b == 0 && t < L) dout[V + 2 * H + t] = s_aw[t];   // attn_weights out
    }
    grid.sync();

    // ---- Phase 2: x = relu(comb_W @ comb_in + comb_b) (waves 0..1023 = blocks 0..255) ----
    if (gw < H) {
        const float4* wrow = (const float4*)(comb_W + (size_t)gw * (2 * H));
        const float4* cin  = (const float4*)(ws + WS_COMB_IN);
        float acc = 0.f;
        #pragma unroll
        for (int it = 0; it < 8; ++it) acc += dot4(wrow[lane + it * 64], cin[lane + it * 64]);
        acc = wave_sum(acc);
        if (lane == 0) ws[WS_X + gw] = fmaxf(acc + comb_b[gw], 0.f);
    }
    grid.sync();

    // ---- Phase 3: LSTM cell. block handles k = b, b+NBLK; wave w -> gate row w*H+k ----
    for (int k = b; k < H; k += NBLK) {
        const int row = w * H + k;
        const float4* wi = (const float4*)(W_ih + (size_t)row * H);
        const float4* wh = (const float4*)(W_hh + (size_t)row * H);
        const float4* xv = (const float4*)(ws + WS_X);
        const float4* hv = (const float4*)h0;
        float acc = 0.f;
        #pragma unroll
        for (int it = 0; it < 4; ++it) {
            acc += dot4(wi[lane + it * 64], xv[lane + it * 64]);
            acc += dot4(wh[lane + it * 64], hv[lane + it * 64]);
        }
        acc = wave_sum(acc);
        if (lane == 0) s_g4[w] = acc + b_ih[row] + b_hh[row];
        __syncthreads();
        if (t == 0) {
            const float gi = sigmoidf(s_g4[0]);
            const float gf = sigmoidf(s_g4[1]);
            const float gg = tanhf(s_g4[2]);
            const float go = sigmoidf(s_g4[3]);
            const float cn = gf * c0[k] + gi * gg;
            const float hn = go * tanhf(cn);
            dout[V + k]     = hn;
            dout[V + H + k] = cn;
            ws[WS_HN + k]   = hn;
        }
        __syncthreads();
    }
    grid.sync();

    // ---- Phase 4: logits GEMV (grid-stride, wave per row) + per-block (m,s) partials ----
    {
        float mloc = -FLT_MAX, sloc = 0.f;          // valid in lane 0 only
        const float4* hv4 = (const float4*)(ws + WS_HN);
        for (int r = gw; r < V; r += NWAVE) {
            const float4* wrow = (const float4*)(out_W + (size_t)r * H);
            float acc = 0.f;
            #pragma unroll
            for (int it = 0; it < 4; ++it) acc += dot4(wrow[lane + it * 64], hv4[lane + it * 64]);
            acc = wave_sum(acc);
            if (lane == 0) {
                const float zz = acc + out_b[r];
                ws[WS_LOGITS + r] = zz;
                if (zz > mloc) { sloc = sloc * expf(mloc - zz) + 1.f; mloc = zz; }
                else           { sloc += expf(zz - mloc); }
            }
        }
        if (lane == 0) { s_redA[w] = mloc; s_redB[w] = sloc; }
        __syncthreads();
        if (t == 0) {
            float m = fmaxf(fmaxf(s_redA[0], s_redA[1]), fmaxf(s_redA[2], s_redA[3]));
            float s = s_redB[0] * expf(s_redA[0] - m) + s_redB[1] * expf(s_redA[1] - m)
                    + s_redB[2] * expf(s_redA[2] - m) + s_redB[3] * expf(s_redA[3] - m);
            ws[WS_PM + b] = m;
            ws[WS_PS + b] = s;
        }
        __syncthreads();
    }
    grid.sync();

    // ---- Phase 5: every block merges the NBLK partials -> lse; subtract & store ----
    {
        float m = -FLT_MAX, s = 0.f;
        for (int i = t; i < NBLK; i += NTHR) {
            const float mi = ws[WS_PM + i], si = ws[WS_PS + i];
            if (mi > m) { s = s * expf(m - mi) + si; m = mi; }
            else        { s += si * expf(mi - m); }
        }
        s_redA[t] = m; s_redB[t] = s;
        __syncthreads();
        #pragma unroll
        for (int st = 128; st > 0; st >>= 1) {
            if (t < st) {
                const float m2 = s_redA[t + st], s2 = s_redB[t + st];
                const float mm = fmaxf(s_redA[t], m2);
                s_redB[t] = s_redB[t] * expf(s_redA[t] - mm) + s2 * expf(m2 - mm);
                s_redA[t] = mm;
            }
            __syncthreads();
        }
        const float lse = s_redA[0] + logf(s_redB[0]);
        const int v = b * NTHR + t;
        if (v < V) dout[v] = ws[WS_LOGITS + v] - lse;
    }
}

extern "C" void kernel_launch(void* const* d_in, const int* in_sizes, int n_in,
                              void* d_out, int out_size, void* d_ws, size_t ws_size,
                              hipStream_t stream) {
    const int*   tokens = (const int*)  d_in[0];
    const float* h0     = (const float*)d_in[1];
    const float* c0     = (const float*)d_in[2];
    const float* enc    = (const float*)d_in[3];
    const float* emb    = (const float*)d_in[4];
    const float* attn_W = (const float*)d_in[5];
    const float* attn_b = (const float*)d_in[6];
    const float* comb_W = (const float*)d_in[7];
    const float* comb_b = (const float*)d_in[8];
    const float* W_ih   = (const float*)d_in[9];
    const float* W_hh   = (const float*)d_in[10];
    const float* b_ih   = (const float*)d_in[11];
    const float* b_hh   = (const float*)d_in[12];
    const float* out_W  = (const float*)d_in[13];
    const float* out_b  = (const float*)d_in[14];
    float* dout = (float*)d_out;
    float* wsp  = (float*)d_ws;

    void* args[] = {
        (void*)&tokens, (void*)&h0, (void*)&c0, (void*)&enc, (void*)&emb,
        (void*)&attn_W, (void*)&attn_b, (void*)&comb_W, (void*)&comb_b,
        (void*)&W_ih, (void*)&W_hh, (void*)&b_ih, (void*)&b_hh,
        (void*)&out_W, (void*)&out_b, (void*)&dout, (void*)&wsp
    };
    hipLaunchCooperativeKernel(reinterpret_cast<void*>(fused_decoder),
                               dim3(NBLK), dim3(NTHR), args, 0, stream);
}